// Round 4
// baseline (584.219 us; speedup 1.0000x reference)
//
#include <hip/hip_runtime.h>
#include <hip/hip_bf16.h>

// Problem constants
#define BB 64
#define SS 2048
#define DD 512
#define MM (BB * SS)  // 131072 rows

typedef __attribute__((ext_vector_type(8))) short bf16x8;
typedef __attribute__((ext_vector_type(4))) float f32x4;

// fp32 -> bf16 bits, round-to-nearest-even
__device__ __forceinline__ unsigned f2bf(float f) {
    unsigned u = __float_as_uint(f);
    u += 0x7FFFu + ((u >> 16) & 1u);
    return u >> 16;
}

__device__ __forceinline__ float fast_tanh(float x) {
    float ax = fabsf(x);
    float e = __expf(-2.0f * ax);                       // (0,1], never overflows
    float t = (1.0f - e) * __builtin_amdgcn_rcpf(1.0f + e);
    return x < 0.0f ? -t : t;
}

// ---------------------------------------------------------------------------
// enc fp32 -> bf16 row-major copy (streaming, memory-bound)
__global__ void cvt_enc(const float* __restrict__ enc, short* __restrict__ enc16) {
    size_t i = ((size_t)blockIdx.x * 256 + threadIdx.x) * 8;
    f32x4 a = *(const f32x4*)(enc + i);
    f32x4 b = *(const f32x4*)(enc + i + 4);
    int4 pk;
    pk.x = f2bf(a.x) | (f2bf(a.y) << 16);
    pk.y = f2bf(a.z) | (f2bf(a.w) << 16);
    pk.z = f2bf(b.x) | (f2bf(b.y) << 16);
    pk.w = f2bf(b.z) | (f2bf(b.w) << 16);
    *(int4*)(enc16 + i) = pk;
}

// ---------------------------------------------------------------------------
// Prep 1: Bt[n][k] = bf16(W_t[512+k][n]).  64x64 LDS tile transpose.
__global__ void prep_w(const float* __restrict__ W, short* __restrict__ Bt) {
    __shared__ float tile[64][65];
    int kt = blockIdx.x >> 3;      // 8 x 8 tiles
    int nt = blockIdx.x & 7;
    int t = threadIdx.x;
    int c = t & 63;
    int rbase = (t >> 6) * 16;
    #pragma unroll
    for (int i = 0; i < 16; ++i) {
        int r = rbase + i;
        tile[r][c] = W[(size_t)(512 + kt * 64 + r) * DD + nt * 64 + c];
    }
    __syncthreads();
    #pragma unroll
    for (int i = 0; i < 16; ++i) {
        int r = rbase + i;
        Bt[(size_t)(nt * 64 + r) * DD + kt * 64 + c] = (short)f2bf(tile[c][r]);
    }
}

// Prep 2: p[b][d] = sum_e dec[b][e] * W_t[e][d] + b_t[d]   (fp32, exact)
__global__ void prep_p(const float* __restrict__ dec, const float* __restrict__ W,
                       const float* __restrict__ bt, float* __restrict__ p) {
    int b = blockIdx.x;
    int d = blockIdx.y * 256 + threadIdx.x;
    float acc = bt[d];
    const float* dv = dec + (size_t)b * DD;
    #pragma unroll 8
    for (int e = 0; e < DD; ++e)
        acc += dv[e] * W[(size_t)e * DD + d];
    p[(size_t)b * DD + d] = acc;
}

// ---------------------------------------------------------------------------
// Score GEMM v4: both A and B staged via global_load_lds (no VALU cvt in-loop).
//   score[m] += sum_{n in slice} tanh(p[b][n] + sum_k enc16[m][k]*Wenc[k][n]) * v[n]
// BM=128, BN=128 (4-way n-split), BK=32, 16 k-iters. 4 waves, wave tile 64x64.
// acc = 64 regs; total regs < 128 -> 4 blocks/CU for inter-block latency hiding.
__global__ __launch_bounds__(256, 4)
void score_gemm(const short* __restrict__ enc16, // bf16 bits [131072][512]
                const short* __restrict__ Bt,    // bf16 bits [512][512] (n-major)
                const float* __restrict__ p,     // [64][512]
                const float* __restrict__ va,    // [512]
                float* __restrict__ score) {     // [131072], pre-zeroed
    __shared__ short Alds[2][128 * 32];   // 2 x 8 KB  [row][k]
    __shared__ short Blds[2][128 * 32];   // 2 x 8 KB  [n][k]
    __shared__ float sp[4][64];

    const int tid  = threadIdx.x;
    const int wave = tid >> 6;
    const int lane = tid & 63;
    const int mblk = blockIdx.x >> 2;
    const int n0   = (blockIdx.x & 3) * 128;   // adjacent n-split blocks -> L2 reuse of A
    const int m0   = mblk * 128;

    const int wm = wave >> 1, wn = wave & 1;
    const int lm = lane & 15, lq = lane >> 4;

    f32x4 acc[4][4];
    #pragma unroll
    for (int i = 0; i < 4; ++i)
        #pragma unroll
        for (int j = 0; j < 4; ++j)
            acc[i][j] = (f32x4){0.f, 0.f, 0.f, 0.f};

    // Staging: wave w covers rows [w*32, w*32+32) of both tiles, 2 issues x 16 rows;
    // lane l -> row +(l>>2), 16B chunk (l&3)*8 shorts.
    const short* aptr = enc16 + (size_t)(m0 + wave * 32 + (lane >> 2)) * DD + (lane & 3) * 8;
    const short* bptr = Bt    + (size_t)(n0 + wave * 32 + (lane >> 2)) * DD + (lane & 3) * 8;

    // ---- prologue: stage kt=0 into buf 0
    #pragma unroll
    for (int i = 0; i < 2; ++i) {
        __builtin_amdgcn_global_load_lds(
            (const __attribute__((address_space(1))) void*)(aptr + (size_t)i * 16 * DD),
            (__attribute__((address_space(3))) void*)(&Alds[0][(wave * 32 + i * 16) * 32]),
            16, 0, 0);
        __builtin_amdgcn_global_load_lds(
            (const __attribute__((address_space(1))) void*)(bptr + (size_t)i * 16 * DD),
            (__attribute__((address_space(3))) void*)(&Blds[0][(wave * 32 + i * 16) * 32]),
            16, 0, 0);
    }
    __syncthreads();

    for (int kt = 0; kt < 16; ++kt) {
        const int c = kt & 1;
        if (kt < 15) {
            const int kn = (kt + 1) * 32;
            #pragma unroll
            for (int i = 0; i < 2; ++i) {
                __builtin_amdgcn_global_load_lds(
                    (const __attribute__((address_space(1))) void*)(aptr + (size_t)i * 16 * DD + kn),
                    (__attribute__((address_space(3))) void*)(&Alds[1 - c][(wave * 32 + i * 16) * 32]),
                    16, 0, 0);
                __builtin_amdgcn_global_load_lds(
                    (const __attribute__((address_space(1))) void*)(bptr + (size_t)i * 16 * DD + kn),
                    (__attribute__((address_space(3))) void*)(&Blds[1 - c][(wave * 32 + i * 16) * 32]),
                    16, 0, 0);
            }
        }
        // ---- compute from buf c
        bf16x8 af[4];
        #pragma unroll
        for (int mf = 0; mf < 4; ++mf)
            af[mf] = *(const bf16x8*)(&Alds[c][(wm * 64 + mf * 16 + lm) * 32 + lq * 8]);
        #pragma unroll
        for (int nf = 0; nf < 4; ++nf) {
            bf16x8 bfr = *(const bf16x8*)(&Blds[c][(wn * 64 + nf * 16 + lm) * 32 + lq * 8]);
            #pragma unroll
            for (int mf = 0; mf < 4; ++mf)
                acc[mf][nf] = __builtin_amdgcn_mfma_f32_16x16x32_bf16(af[mf], bfr, acc[mf][nf], 0, 0, 0);
        }
        __syncthreads();
    }

    // ---- epilogue: tanh + dot with v over this block's n-slice, then atomicAdd
    const int b = m0 >> 11;  // m0 / 2048 (BM=128 never straddles a batch)
    float rowsum[4][4];
    #pragma unroll
    for (int mf = 0; mf < 4; ++mf)
        #pragma unroll
        for (int r = 0; r < 4; ++r) rowsum[mf][r] = 0.f;

    #pragma unroll
    for (int nf = 0; nf < 4; ++nf) {
        int n = n0 + wn * 64 + nf * 16 + lm;
        float pv = p[(size_t)b * DD + n];
        float vv = va[n];
        #pragma unroll
        for (int mf = 0; mf < 4; ++mf)
            #pragma unroll
            for (int r = 0; r < 4; ++r)
                rowsum[mf][r] += fast_tanh(pv + acc[mf][nf][r]) * vv;
    }
    #pragma unroll
    for (int mf = 0; mf < 4; ++mf)
        #pragma unroll
        for (int r = 0; r < 4; ++r) {
            float s = rowsum[mf][r];
            s += __shfl_xor(s, 1);
            s += __shfl_xor(s, 2);
            s += __shfl_xor(s, 4);
            s += __shfl_xor(s, 8);
            rowsum[mf][r] = s;
        }
    if (lm == 0) {
        #pragma unroll
        for (int mf = 0; mf < 4; ++mf)
            #pragma unroll
            for (int r = 0; r < 4; ++r)
                sp[wave][mf * 16 + lq * 4 + r] = rowsum[mf][r];
    }
    __syncthreads();
    if (tid < 128) {
        int row = tid & 63, half = tid >> 6;
        float v = sp[half * 2][row] + sp[half * 2 + 1][row];
        atomicAdd(&score[(size_t)m0 + half * 64 + row], v);
    }
}

// ---------------------------------------------------------------------------
// Fallback score GEMM (round-3 version, fp32 enc, in-kernel cvt) — used only
// if ws_size can't hold the bf16 enc copy.
__global__ __launch_bounds__(256, 2)
void score_gemm_f32(const float* __restrict__ enc,
                    const short* __restrict__ Bt,
                    const float* __restrict__ p,
                    const float* __restrict__ va,
                    float* __restrict__ score) {
    __shared__ short Alds[2][128 * 32];
    __shared__ short Blds[2][128 * 32];
    __shared__ float sp[4][64];

    const int tid  = threadIdx.x;
    const int wave = tid >> 6;
    const int lane = tid & 63;
    const int mblk = blockIdx.x >> 2;
    const int n0   = (blockIdx.x & 3) * 128;
    const int m0   = mblk * 128;

    const int wm = wave >> 1, wn = wave & 1;
    const int lm = lane & 15, lq = lane >> 4;

    f32x4 acc[4][4];
    #pragma unroll
    for (int i = 0; i < 4; ++i)
        #pragma unroll
        for (int j = 0; j < 4; ++j)
            acc[i][j] = (f32x4){0.f, 0.f, 0.f, 0.f};

    const int arow = tid >> 1;
    const int acol = (tid & 1) * 16;
    const float* aptr = enc + (size_t)(m0 + arow) * DD + acol;
    const short* bptr = Bt + (size_t)(n0 + wave * 32 + (lane >> 2)) * DD + (lane & 3) * 8;

    #pragma unroll
    for (int i = 0; i < 2; ++i)
        __builtin_amdgcn_global_load_lds(
            (const __attribute__((address_space(1))) void*)(bptr + (size_t)i * 16 * DD),
            (__attribute__((address_space(3))) void*)(&Blds[0][(wave * 32 + i * 16) * 32]),
            16, 0, 0);
    {
        f32x4 x0 = *(const f32x4*)(aptr);
        f32x4 x1 = *(const f32x4*)(aptr + 4);
        f32x4 x2 = *(const f32x4*)(aptr + 8);
        f32x4 x3 = *(const f32x4*)(aptr + 12);
        int4 p0, p1;
        p0.x = f2bf(x0.x) | (f2bf(x0.y) << 16);
        p0.y = f2bf(x0.z) | (f2bf(x0.w) << 16);
        p0.z = f2bf(x1.x) | (f2bf(x1.y) << 16);
        p0.w = f2bf(x1.z) | (f2bf(x1.w) << 16);
        p1.x = f2bf(x2.x) | (f2bf(x2.y) << 16);
        p1.y = f2bf(x2.z) | (f2bf(x2.w) << 16);
        p1.z = f2bf(x3.x) | (f2bf(x3.y) << 16);
        p1.w = f2bf(x3.z) | (f2bf(x3.w) << 16);
        *(int4*)(&Alds[0][arow * 32 + acol]) = p0;
        *(int4*)(&Alds[0][arow * 32 + acol + 8]) = p1;
    }
    __syncthreads();

    for (int kt = 0; kt < 16; ++kt) {
        const int c = kt & 1;
        const bool pf = kt < 15;
        f32x4 x0, x1, x2, x3;
        if (pf) {
            const int kn = (kt + 1) * 32;
            #pragma unroll
            for (int i = 0; i < 2; ++i)
                __builtin_amdgcn_global_load_lds(
                    (const __attribute__((address_space(1))) void*)(bptr + (size_t)i * 16 * DD + kn),
                    (__attribute__((address_space(3))) void*)(&Blds[1 - c][(wave * 32 + i * 16) * 32]),
                    16, 0, 0);
            x0 = *(const f32x4*)(aptr + kn);
            x1 = *(const f32x4*)(aptr + kn + 4);
            x2 = *(const f32x4*)(aptr + kn + 8);
            x3 = *(const f32x4*)(aptr + kn + 12);
        }
        bf16x8 af[4];
        #pragma unroll
        for (int mf = 0; mf < 4; ++mf)
            af[mf] = *(const bf16x8*)(&Alds[c][(wm * 64 + mf * 16 + lm) * 32 + lq * 8]);
        #pragma unroll
        for (int nf = 0; nf < 4; ++nf) {
            bf16x8 bfr = *(const bf16x8*)(&Blds[c][(wn * 64 + nf * 16 + lm) * 32 + lq * 8]);
            #pragma unroll
            for (int mf = 0; mf < 4; ++mf)
                acc[mf][nf] = __builtin_amdgcn_mfma_f32_16x16x32_bf16(af[mf], bfr, acc[mf][nf], 0, 0, 0);
        }
        if (pf) {
            int4 p0, p1;
            p0.x = f2bf(x0.x) | (f2bf(x0.y) << 16);
            p0.y = f2bf(x0.z) | (f2bf(x0.w) << 16);
            p0.z = f2bf(x1.x) | (f2bf(x1.y) << 16);
            p0.w = f2bf(x1.z) | (f2bf(x1.w) << 16);
            p1.x = f2bf(x2.x) | (f2bf(x2.y) << 16);
            p1.y = f2bf(x2.z) | (f2bf(x2.w) << 16);
            p1.z = f2bf(x3.x) | (f2bf(x3.y) << 16);
            p1.w = f2bf(x3.z) | (f2bf(x3.w) << 16);
            *(int4*)(&Alds[1 - c][arow * 32 + acol]) = p0;
            *(int4*)(&Alds[1 - c][arow * 32 + acol + 8]) = p1;
        }
        __syncthreads();
    }

    const int b = m0 >> 11;
    float rowsum[4][4];
    #pragma unroll
    for (int mf = 0; mf < 4; ++mf)
        #pragma unroll
        for (int r = 0; r < 4; ++r) rowsum[mf][r] = 0.f;

    #pragma unroll
    for (int nf = 0; nf < 4; ++nf) {
        int n = n0 + wn * 64 + nf * 16 + lm;
        float pv = p[(size_t)b * DD + n];
        float vv = va[n];
        #pragma unroll
        for (int mf = 0; mf < 4; ++mf)
            #pragma unroll
            for (int r = 0; r < 4; ++r)
                rowsum[mf][r] += fast_tanh(pv + acc[mf][nf][r]) * vv;
    }
    #pragma unroll
    for (int mf = 0; mf < 4; ++mf)
        #pragma unroll
        for (int r = 0; r < 4; ++r) {
            float s = rowsum[mf][r];
            s += __shfl_xor(s, 1);
            s += __shfl_xor(s, 2);
            s += __shfl_xor(s, 4);
            s += __shfl_xor(s, 8);
            rowsum[mf][r] = s;
        }
    if (lm == 0) {
        #pragma unroll
        for (int mf = 0; mf < 4; ++mf)
            #pragma unroll
            for (int r = 0; r < 4; ++r)
                sp[wave][mf * 16 + lq * 4 + r] = rowsum[mf][r];
    }
    __syncthreads();
    if (tid < 128) {
        int row = tid & 63, half = tid >> 6;
        float v = sp[half * 2][row] + sp[half * 2 + 1][row];
        atomicAdd(&score[(size_t)m0 + half * 64 + row], v);
    }
}

// ---------------------------------------------------------------------------
// Softmax over S per batch; writes alignment (output 1). b_v dropped: softmax
// is shift-invariant, so both outputs are unchanged.
__global__ void softmax_k(const float* __restrict__ score, float* __restrict__ align) {
    __shared__ float red[256];
    int b = blockIdx.x, tid = threadIdx.x;
    const float* s = score + (size_t)b * SS;
    float vals[8];
    float mx = -1e30f;
    #pragma unroll
    for (int i = 0; i < 8; ++i) {
        vals[i] = s[i * 256 + tid];
        mx = fmaxf(mx, vals[i]);
    }
    red[tid] = mx; __syncthreads();
    for (int off = 128; off > 0; off >>= 1) {
        if (tid < off) red[tid] = fmaxf(red[tid], red[tid + off]);
        __syncthreads();
    }
    mx = red[0]; __syncthreads();
    float sum = 0.f;
    #pragma unroll
    for (int i = 0; i < 8; ++i) {
        vals[i] = __expf(vals[i] - mx);
        sum += vals[i];
    }
    red[tid] = sum; __syncthreads();
    for (int off = 128; off > 0; off >>= 1) {
        if (tid < off) red[tid] += red[tid + off];
        __syncthreads();
    }
    float inv = 1.0f / red[0];
    #pragma unroll
    for (int i = 0; i < 8; ++i)
        align[(size_t)b * SS + i * 256 + tid] = vals[i] * inv;
}

// ---------------------------------------------------------------------------
// context[b][d] = sum_s align[b][s] * enc[b][s][d]   (atomic accumulate)
__global__ void context_k(const float* __restrict__ enc, const float* __restrict__ align,
                          float* __restrict__ ctx) {
    int bx = blockIdx.x;           // 64 * 16
    int b = bx >> 4, chunk = bx & 15;
    int tid = threadIdx.x;         // 256 threads, float2 each => 512 cols
    const float2* e2 = (const float2*)(enc + ((size_t)b * SS + chunk * 128) * DD);
    const float* a = align + (size_t)b * SS + chunk * 128;
    float2 acc = {0.f, 0.f};
    #pragma unroll 4
    for (int s = 0; s < 128; ++s) {
        float av = a[s];
        float2 e = e2[(size_t)s * 256 + tid];
        acc.x += av * e.x;
        acc.y += av * e.y;
    }
    atomicAdd(&ctx[(size_t)b * DD + tid * 2], acc.x);
    atomicAdd(&ctx[(size_t)b * DD + tid * 2 + 1], acc.y);
}

// ---------------------------------------------------------------------------
extern "C" void kernel_launch(void* const* d_in, const int* in_sizes, int n_in,
                              void* d_out, int out_size, void* d_ws, size_t ws_size,
                              hipStream_t stream) {
    const float* dec = (const float*)d_in[0];  // [64,1,512]
    const float* enc = (const float*)d_in[1];  // [64,2048,512]
    const float* W   = (const float*)d_in[2];  // [1024,512]
    const float* bt  = (const float*)d_in[3];  // [512]
    const float* va  = (const float*)d_in[4];  // [512,1]

    float* out   = (float*)d_out;
    float* ctx   = out;                 // 32768 floats (output 0)
    float* align = out + BB * DD;       // 131072 floats (output 1)

    const size_t enc16_bytes = (size_t)MM * DD * 2;          // 128 MB
    const size_t small_bytes = 512 * 1024 + 128 * 1024 + 512 * 1024;
    char* ws = (char*)d_ws;

    if (ws_size >= enc16_bytes + small_bytes) {
        short* enc16 = (short*)ws;
        short* Bt    = (short*)(ws + enc16_bytes);
        float* p     = (float*)(ws + enc16_bytes + 512 * 1024);
        float* score = (float*)(ws + enc16_bytes + 512 * 1024 + 128 * 1024);

        hipMemsetAsync(ctx, 0, BB * DD * sizeof(float), stream);
        hipMemsetAsync(score, 0, MM * sizeof(float), stream);
        cvt_enc<<<(MM * DD) / (256 * 8), 256, 0, stream>>>(enc, enc16);
        prep_w<<<64, 256, 0, stream>>>(W, Bt);
        prep_p<<<dim3(BB, 2), 256, 0, stream>>>(dec, W, bt, p);
        score_gemm<<<MM / 32, 256, 0, stream>>>(enc16, Bt, p, va, score);
        softmax_k<<<BB, 256, 0, stream>>>(score, align);
        context_k<<<BB * 16, 256, 0, stream>>>(enc, align, ctx);
    } else {
        short* Bt    = (short*)ws;
        float* p     = (float*)(ws + 512 * 1024);
        float* score = (float*)(ws + 512 * 1024 + 128 * 1024);

        hipMemsetAsync(ctx, 0, BB * DD * sizeof(float), stream);
        hipMemsetAsync(score, 0, MM * sizeof(float), stream);
        prep_w<<<64, 256, 0, stream>>>(W, Bt);
        prep_p<<<dim3(BB, 2), 256, 0, stream>>>(dec, W, bt, p);
        score_gemm_f32<<<MM / 32, 256, 0, stream>>>(enc, Bt, p, va, score);
        softmax_k<<<BB, 256, 0, stream>>>(score, align);
        context_k<<<BB * 16, 256, 0, stream>>>(enc, align, ctx);
    }
}